// Round 5
// baseline (346.617 us; speedup 1.0000x reference)
//
#include <hip/hip_runtime.h>
#include <hip/hip_bf16.h>
#include <math.h>

#define N_TOKENS 16384
#define DIM      4096
#define NE       64
#define TOPK     8
#define TM       64
#define BK       64
#define XS_STRIDE 68   // 64 + 4 pad

// Reproduce OpenBLAS sgemm (SKYLAKEX/COOPERLAKE, Q=320, tail-halved) summation:
// per (token,expert): logit = ((B0 + B1) + ... ) where Bi = ascending-k FMA
// chain over block i, blocks = [320 x 11, 288, 288]; block sums added ascending.

__global__ __launch_bounds__(256) void topk_gating_blas(
    const float* __restrict__ x, const float* __restrict__ w, float* __restrict__ out)
{
    __shared__ float xs[TM * XS_STRIDE];   // x tile [64 tokens][68]
    __shared__ float ws[BK * NE];          // w tile [64 k][64 experts]

    const int tid = threadIdx.x;
    const int eg  = tid & 15;
    const int tg  = tid >> 4;
    const int e0  = eg * 4;
    const int t0  = tg * 4;
    const int bt0 = blockIdx.x * TM;

    float acc[4][4];   // current K-block partial (starts at 0 each block)
    float tot[4][4];   // running sum of completed blocks
#pragma unroll
    for (int i = 0; i < 4; ++i)
#pragma unroll
        for (int j = 0; j < 4; ++j) { acc[i][j] = 0.0f; tot[i][j] = 0.0f; }

    const float4* xg = reinterpret_cast<const float4*>(x);
    const float4* wg = reinterpret_cast<const float4*>(w);

    float4 xr[4], wr[4];   // register staging (HBM latency overlaps compute)

    auto load_step = [&](int k0) {
#pragma unroll
        for (int r = 0; r < 4; ++r) {
            int idx = tid + 256 * r;
            int T = idx >> 4;
            int c = idx & 15;
            xr[r] = xg[(size_t)(bt0 + T) * (DIM / 4) + (k0 >> 2) + c];
            wr[r] = wg[(size_t)(k0 + T) * (NE / 4) + c];
        }
    };
    auto write_step = [&]() {
#pragma unroll
        for (int r = 0; r < 4; ++r) {
            int idx = tid + 256 * r;
            int T = idx >> 4;
            int c = idx & 15;
            *reinterpret_cast<float4*>(&xs[T * XS_STRIDE + c * 4]) = xr[r];
            *reinterpret_cast<float4*>(&ws[T * NE + c * 4])        = wr[r];
        }
    };
    auto fold = [&]() {   // close current K-block: tot += acc; acc = 0
#pragma unroll
        for (int i = 0; i < 4; ++i)
#pragma unroll
            for (int j = 0; j < 4; ++j) { tot[i][j] += acc[i][j]; acc[i][j] = 0.0f; }
    };

    load_step(0);

    for (int s = 0; s < DIM / BK; ++s) {
        __syncthreads();
        write_step();
        __syncthreads();
        if (s + 1 < DIM / BK) load_step((s + 1) * BK);

#pragma unroll
        for (int kq = 0; kq < 16; ++kq) {
            float xf[4][4], wf[4][4];
#pragma unroll
            for (int i = 0; i < 4; ++i)
                *reinterpret_cast<float4*>(xf[i]) =
                    *reinterpret_cast<const float4*>(&xs[(t0 + i) * XS_STRIDE + kq * 4]);
#pragma unroll
            for (int kk = 0; kk < 4; ++kk)
                *reinterpret_cast<float4*>(wf[kk]) =
                    *reinterpret_cast<const float4*>(&ws[(kq * 4 + kk) * NE + e0]);
            // ascending k per (i,j), FMA (matches AVX512 vfmadd chain)
#pragma unroll
            for (int kk = 0; kk < 4; ++kk)
#pragma unroll
                for (int i = 0; i < 4; ++i)
#pragma unroll
                    for (int j = 0; j < 4; ++j)
                        acc[i][j] = fmaf(xf[i][kk], wf[kk][j], acc[i][j]);
            // block boundary at k=3808 (after kq==7 of step 59): tail halves 288/288
            if (kq == 7 && s == 59) fold();
        }
        // block boundaries at k = 320*b (b=1..11): after steps 4,9,...,54
        if ((s % 5) == 4 && s <= 54) fold();
    }
    fold();   // final block

    // ---- Epilogue: logits -> LDS; rank on LOGITS (monotone == gate rank) ----
    __syncthreads();
#pragma unroll
    for (int i = 0; i < 4; ++i)
        *reinterpret_cast<float4*>(&xs[(t0 + i) * XS_STRIDE + e0]) =
            *reinterpret_cast<float4*>(tot[i]);
    __syncthreads();

    const int lane = tid & 63;
    const int wid  = tid >> 6;
    float* outI = out;
    float* outG = out + (size_t)N_TOKENS * TOPK;

    for (int tt = 0; tt < 16; ++tt) {
        const int t = wid * 16 + tt;
        float v = xs[t * XS_STRIDE + lane];   // lane = expert, logit

        // fp32 softmax values (for output 1 only; ranking uses logits)
        float m = v;
#pragma unroll
        for (int off = 32; off; off >>= 1) m = fmaxf(m, __shfl_xor(m, off));
        float e = expf(v - m);
        float ssum = e;
#pragma unroll
        for (int off = 32; off; off >>= 1) ssum += __shfl_xor(ssum, off);
        float g = e / ssum;

        // top-8 on logits, ties -> lower index
        float curv = v;
        const int idx = lane;
        float myi = 0.0f, myg = 0.0f;
#pragma unroll
        for (int r = 0; r < TOPK; ++r) {
            float bv = curv;
            int   bi = idx;
#pragma unroll
            for (int off = 32; off; off >>= 1) {
                float ov = __shfl_xor(bv, off);
                int   oi = __shfl_xor(bi, off);
                if (ov > bv || (ov == bv && oi < bi)) { bv = ov; bi = oi; }
            }
            float wg = __shfl(g, bi);          // winner's gate value
            if (lane == r) { myi = (float)bi; myg = wg; }
            if (idx == bi) curv = -INFINITY;   // remove winner
        }
        const int gt = bt0 + t;
        if (lane < TOPK) {
            outI[(size_t)gt * TOPK + lane] = myi;
            outG[(size_t)gt * TOPK + lane] = myg;
        }
    }
}

extern "C" void kernel_launch(void* const* d_in, const int* in_sizes, int n_in,
                              void* d_out, int out_size, void* d_ws, size_t ws_size,
                              hipStream_t stream) {
    const float* x = (const float*)d_in[0];
    const float* w = (const float*)d_in[1];
    float* out = (float*)d_out;
    topk_gating_blas<<<dim3(N_TOKENS / TM), dim3(256), 0, stream>>>(x, w, out);
}

// Round 6
// 291.832 us; speedup vs baseline: 1.1877x; 1.1877x over previous
//
#include <hip/hip_runtime.h>
#include <hip/hip_bf16.h>
#include <math.h>

#define N_TOKENS 16384
#define DIM      4096
#define NE       64
#define TOPK     8
#define TM       64
#define NCHUNK   13     // OpenBLAS Kc blocks: [320 x 11, 288, 288]
#define XS2      36     // pass1 x-row stride (32 + 4 pad)
#define XSE      68     // epilogue logits stride (64 + 4 pad)
#define NTILE    (N_TOKENS / TM)   // 256 token tiles

// ---------------- Pass 1: one OpenBLAS K-chunk per block.y ----------------
// Each (tile, b) block computes the pure ascending-k FMA chain over its chunk
// (starting from 0 — chunk boundaries ARE the reference's fold points), and
// writes the 64x64 fp32 partial to part[tile][b][tok][exp].
__global__ __launch_bounds__(256, 3) void gate_pass1(
    const float* __restrict__ x, const float* __restrict__ w, float* __restrict__ part)
{
    __shared__ float xs[TM * XS2];   // x tile [64 tok][36]
    __shared__ float ws[32 * NE];    // w tile [32 k][64 exp]

    const int tid = threadIdx.x;
    const int eg  = tid & 15;
    const int tg  = tid >> 4;
    const int e0  = eg * 4;
    const int t0  = tg * 4;
    const int bt0 = blockIdx.x * TM;
    const int b   = blockIdx.y;
    const int kstart = (b < 12) ? 320 * b : 3808;
    const int nsteps = (b < 11) ? 10 : 9;          // 320 = 10*32, 288 = 9*32

    float acc[4][4];
#pragma unroll
    for (int i = 0; i < 4; ++i)
#pragma unroll
        for (int j = 0; j < 4; ++j) acc[i][j] = 0.0f;

    const float4* xg = reinterpret_cast<const float4*>(x);
    const float4* wg = reinterpret_cast<const float4*>(w);
    float4 xr[2], wr[2];

    auto load_step = [&](int k0) {
#pragma unroll
        for (int r = 0; r < 2; ++r) {
            int idx = tid + 256 * r;             // 0..511
            int Tx = idx >> 3, cx = idx & 7;     // x: 64 rows x 8 float4
            xr[r] = xg[(size_t)(bt0 + Tx) * (DIM / 4) + (k0 >> 2) + cx];
            int Tw = idx >> 4, cw = idx & 15;    // w: 32 rows x 16 float4
            wr[r] = wg[(size_t)(k0 + Tw) * (NE / 4) + cw];
        }
    };
    auto write_step = [&]() {
#pragma unroll
        for (int r = 0; r < 2; ++r) {
            int idx = tid + 256 * r;
            int Tx = idx >> 3, cx = idx & 7;
            *reinterpret_cast<float4*>(&xs[Tx * XS2 + cx * 4]) = xr[r];
            int Tw = idx >> 4, cw = idx & 15;
            *reinterpret_cast<float4*>(&ws[Tw * NE + cw * 4]) = wr[r];
        }
    };

    load_step(kstart);
    for (int s = 0; s < nsteps; ++s) {
        __syncthreads();
        write_step();
        __syncthreads();
        if (s + 1 < nsteps) load_step(kstart + 32 * (s + 1));

#pragma unroll
        for (int kq = 0; kq < 8; ++kq) {
            float xf[4][4], wf[4][4];
#pragma unroll
            for (int i = 0; i < 4; ++i)
                *reinterpret_cast<float4*>(xf[i]) =
                    *reinterpret_cast<const float4*>(&xs[(t0 + i) * XS2 + kq * 4]);
#pragma unroll
            for (int kk = 0; kk < 4; ++kk)
                *reinterpret_cast<float4*>(wf[kk]) =
                    *reinterpret_cast<const float4*>(&ws[(kq * 4 + kk) * NE + e0]);
            // k strictly ascending per (i,j), FMA — matches BLAS inner chain
#pragma unroll
            for (int kk = 0; kk < 4; ++kk)
#pragma unroll
                for (int i = 0; i < 4; ++i)
#pragma unroll
                    for (int j = 0; j < 4; ++j)
                        acc[i][j] = fmaf(xf[i][kk], wf[kk][j], acc[i][j]);
        }
    }

    float* pt = part + ((size_t)blockIdx.x * NCHUNK + b) * (TM * NE);
#pragma unroll
    for (int i = 0; i < 4; ++i)
        *reinterpret_cast<float4*>(&pt[(t0 + i) * NE + e0]) =
            *reinterpret_cast<float4*>(acc[i]);
}

// ------- Pass 2: fold 13 partials ascending (exact ref tree) + epilogue -------
__global__ __launch_bounds__(256) void gate_pass2(
    const float* __restrict__ part, float* __restrict__ out)
{
    __shared__ float xs[TM * XSE];
    const int tid  = threadIdx.x;
    const int tile = blockIdx.x;
    const float4* p4 = reinterpret_cast<const float4*>(
        part + (size_t)tile * NCHUNK * (TM * NE));
    const int e4 = tid & 15;       // float4 column over experts
    const int tl = tid >> 4;       // 0..15

#pragma unroll
    for (int tq = 0; tq < 4; ++tq) {
        const int tok = tq * 16 + tl;
        float4 tot = make_float4(0.f, 0.f, 0.f, 0.f);
#pragma unroll
        for (int bb = 0; bb < NCHUNK; ++bb) {     // ascending: ((B0+B1)+...)+B12
            float4 p = p4[bb * (TM * NE / 4) + tok * (NE / 4) + e4];
            tot.x += p.x; tot.y += p.y; tot.z += p.z; tot.w += p.w;
        }
        *reinterpret_cast<float4*>(&xs[tok * XSE + e4 * 4]) = tot;
    }
    __syncthreads();

    const int lane = tid & 63;
    const int wid  = tid >> 6;
    float* outI = out;
    float* outG = out + (size_t)N_TOKENS * TOPK;

    for (int tt = 0; tt < 16; ++tt) {
        const int t = wid * 16 + tt;
        float v = xs[t * XSE + lane];   // lane = expert, logit

        float m = v;
#pragma unroll
        for (int off = 32; off; off >>= 1) m = fmaxf(m, __shfl_xor(m, off));
        float e = expf(v - m);
        float ssum = e;
#pragma unroll
        for (int off = 32; off; off >>= 1) ssum += __shfl_xor(ssum, off);
        float g = e / ssum;

        // top-8 on logits (monotone == gate rank), ties -> lower index
        float curv = v;
        const int idx = lane;
        float myi = 0.0f, myg = 0.0f;
#pragma unroll
        for (int r = 0; r < TOPK; ++r) {
            float bv = curv;
            int   bi = idx;
#pragma unroll
            for (int off = 32; off; off >>= 1) {
                float ov = __shfl_xor(bv, off);
                int   oi = __shfl_xor(bi, off);
                if (ov > bv || (ov == bv && oi < bi)) { bv = ov; bi = oi; }
            }
            float wgv = __shfl(g, bi);
            if (lane == r) { myi = (float)bi; myg = wgv; }
            if (idx == bi) curv = -INFINITY;
        }
        const int gt = tile * TM + t;
        if (lane < TOPK) {
            outI[(size_t)gt * TOPK + lane] = myi;
            outG[(size_t)gt * TOPK + lane] = myg;
        }
    }
}

// ---------------- Fallback: verified single-pass round-5 kernel ----------------
#define BK 64
#define XS_STRIDE 68
__global__ __launch_bounds__(256) void topk_gating_blas(
    const float* __restrict__ x, const float* __restrict__ w, float* __restrict__ out)
{
    __shared__ float xs[TM * XS_STRIDE];
    __shared__ float ws[BK * NE];

    const int tid = threadIdx.x;
    const int eg  = tid & 15;
    const int tg  = tid >> 4;
    const int e0  = eg * 4;
    const int t0  = tg * 4;
    const int bt0 = blockIdx.x * TM;

    float acc[4][4], tot[4][4];
#pragma unroll
    for (int i = 0; i < 4; ++i)
#pragma unroll
        for (int j = 0; j < 4; ++j) { acc[i][j] = 0.0f; tot[i][j] = 0.0f; }

    const float4* xg = reinterpret_cast<const float4*>(x);
    const float4* wg = reinterpret_cast<const float4*>(w);
    float4 xr[4], wr[4];

    auto load_step = [&](int k0) {
#pragma unroll
        for (int r = 0; r < 4; ++r) {
            int idx = tid + 256 * r;
            int T = idx >> 4, c = idx & 15;
            xr[r] = xg[(size_t)(bt0 + T) * (DIM / 4) + (k0 >> 2) + c];
            wr[r] = wg[(size_t)(k0 + T) * (NE / 4) + c];
        }
    };
    auto write_step = [&]() {
#pragma unroll
        for (int r = 0; r < 4; ++r) {
            int idx = tid + 256 * r;
            int T = idx >> 4, c = idx & 15;
            *reinterpret_cast<float4*>(&xs[T * XS_STRIDE + c * 4]) = xr[r];
            *reinterpret_cast<float4*>(&ws[T * NE + c * 4])        = wr[r];
        }
    };
    auto fold = [&]() {
#pragma unroll
        for (int i = 0; i < 4; ++i)
#pragma unroll
            for (int j = 0; j < 4; ++j) { tot[i][j] += acc[i][j]; acc[i][j] = 0.0f; }
    };

    load_step(0);
    for (int s = 0; s < DIM / BK; ++s) {
        __syncthreads();
        write_step();
        __syncthreads();
        if (s + 1 < DIM / BK) load_step((s + 1) * BK);
#pragma unroll
        for (int kq = 0; kq < 16; ++kq) {
            float xf[4][4], wf[4][4];
#pragma unroll
            for (int i = 0; i < 4; ++i)
                *reinterpret_cast<float4*>(xf[i]) =
                    *reinterpret_cast<const float4*>(&xs[(t0 + i) * XS_STRIDE + kq * 4]);
#pragma unroll
            for (int kk = 0; kk < 4; ++kk)
                *reinterpret_cast<float4*>(wf[kk]) =
                    *reinterpret_cast<const float4*>(&ws[(kq * 4 + kk) * NE + e0]);
#pragma unroll
            for (int kk = 0; kk < 4; ++kk)
#pragma unroll
                for (int i = 0; i < 4; ++i)
#pragma unroll
                    for (int j = 0; j < 4; ++j)
                        acc[i][j] = fmaf(xf[i][kk], wf[kk][j], acc[i][j]);
            if (kq == 7 && s == 59) fold();
        }
        if ((s % 5) == 4 && s <= 54) fold();
    }
    fold();

    __syncthreads();
#pragma unroll
    for (int i = 0; i < 4; ++i)
        *reinterpret_cast<float4*>(&xs[(t0 + i) * XS_STRIDE + e0]) =
            *reinterpret_cast<float4*>(tot[i]);
    __syncthreads();

    const int lane = tid & 63;
    const int wid  = tid >> 6;
    float* outI = out;
    float* outG = out + (size_t)N_TOKENS * TOPK;

    for (int tt = 0; tt < 16; ++tt) {
        const int t = wid * 16 + tt;
        float v = xs[t * XS_STRIDE + lane];
        float m = v;
#pragma unroll
        for (int off = 32; off; off >>= 1) m = fmaxf(m, __shfl_xor(m, off));
        float e = expf(v - m);
        float ssum = e;
#pragma unroll
        for (int off = 32; off; off >>= 1) ssum += __shfl_xor(ssum, off);
        float g = e / ssum;

        float curv = v;
        const int idx = lane;
        float myi = 0.0f, myg = 0.0f;
#pragma unroll
        for (int r = 0; r < TOPK; ++r) {
            float bv = curv;
            int   bi = idx;
#pragma unroll
            for (int off = 32; off; off >>= 1) {
                float ov = __shfl_xor(bv, off);
                int   oi = __shfl_xor(bi, off);
                if (ov > bv || (ov == bv && oi < bi)) { bv = ov; bi = oi; }
            }
            float wgv = __shfl(g, bi);
            if (lane == r) { myi = (float)bi; myg = wgv; }
            if (idx == bi) curv = -INFINITY;
        }
        const int gt = bt0 + t;
        if (lane < TOPK) {
            outI[(size_t)gt * TOPK + lane] = myi;
            outG[(size_t)gt * TOPK + lane] = myg;
        }
    }
}

extern "C" void kernel_launch(void* const* d_in, const int* in_sizes, int n_in,
                              void* d_out, int out_size, void* d_ws, size_t ws_size,
                              hipStream_t stream) {
    const float* x = (const float*)d_in[0];
    const float* w = (const float*)d_in[1];
    float* out = (float*)d_out;
    const size_t needed = (size_t)NTILE * NCHUNK * TM * NE * sizeof(float);  // 54.5 MB
    if (ws_size >= needed) {
        float* part = (float*)d_ws;
        gate_pass1<<<dim3(NTILE, NCHUNK), dim3(256), 0, stream>>>(x, w, part);
        gate_pass2<<<dim3(NTILE), dim3(256), 0, stream>>>(part, out);
    } else {
        topk_gating_blas<<<dim3(NTILE), dim3(256), 0, stream>>>(x, w, out);
    }
}

// Round 7
// 235.751 us; speedup vs baseline: 1.4703x; 1.2379x over previous
//
#include <hip/hip_runtime.h>
#include <hip/hip_bf16.h>
#include <math.h>

#define N_TOKENS 16384
#define DIM      4096
#define NE       64
#define TOPK     8
#define NCHUNK   13     // OpenBLAS Kc blocks: [320 x 11, 288, 288]
#define TM1      128    // pass1 tokens per block
#define XS1      36     // pass1 x-row stride (32 + 4 pad)
#define NT1      (N_TOKENS / TM1)   // 128 token tiles

// ---------------- Pass 1: one OpenBLAS K-chunk per block.y ----------------
// part layout: part[b][token][expert], b = 0..12
// Micro-tile 8 tokens x 4 experts per thread; thread's tokens are tg + 16*i
// so a wave's 4 unique x-rows are adjacent (bank-conflict-free ds_read_b128).
__global__ __launch_bounds__(256, 4) void gate_pass1(
    const float* __restrict__ x, const float* __restrict__ w, float* __restrict__ part)
{
    __shared__ float xs[TM1 * XS1];  // 18432 B
    __shared__ float ws[32 * NE];    //  8192 B

    const int tid = threadIdx.x;
    const int eg  = tid & 15;        // expert group (4 experts)
    const int tg  = tid >> 4;        // token base 0..15
    const int e0  = eg * 4;
    const int g0  = blockIdx.x * TM1;
    const int b   = blockIdx.y;
    const int kstart = (b < 12) ? 320 * b : 3808;
    const int nsteps = (b < 11) ? 10 : 9;          // 320 = 10*32, 288 = 9*32

    float acc[8][4] __attribute__((aligned(16)));
#pragma unroll
    for (int i = 0; i < 8; ++i)
#pragma unroll
        for (int j = 0; j < 4; ++j) acc[i][j] = 0.0f;

    const float4* xg = reinterpret_cast<const float4*>(x);
    const float4* wg = reinterpret_cast<const float4*>(w);
    float4 xr[4], wr[2];

    auto load_step = [&](int k0) {
#pragma unroll
        for (int r = 0; r < 4; ++r) {             // x: 128 rows x 8 float4
            int idx = tid + 256 * r;
            int row = idx >> 3, col = idx & 7;
            xr[r] = xg[(size_t)(g0 + row) * (DIM / 4) + (k0 >> 2) + col];
        }
#pragma unroll
        for (int r = 0; r < 2; ++r) {             // w: 32 rows x 16 float4
            int idx = tid + 256 * r;
            int row = idx >> 4, col = idx & 15;
            wr[r] = wg[(size_t)(k0 + row) * (NE / 4) + col];
        }
    };
    auto write_step = [&]() {
#pragma unroll
        for (int r = 0; r < 4; ++r) {
            int idx = tid + 256 * r;
            int row = idx >> 3, col = idx & 7;
            *reinterpret_cast<float4*>(&xs[row * XS1 + col * 4]) = xr[r];
        }
#pragma unroll
        for (int r = 0; r < 2; ++r) {
            int idx = tid + 256 * r;
            int row = idx >> 4, col = idx & 15;
            *reinterpret_cast<float4*>(&ws[row * NE + col * 4]) = wr[r];
        }
    };

    load_step(kstart);
    for (int s = 0; s < nsteps; ++s) {
        __syncthreads();
        write_step();
        __syncthreads();
        if (s + 1 < nsteps) load_step(kstart + 32 * (s + 1));

#pragma unroll
        for (int kq = 0; kq < 8; ++kq) {
            float wf[4][4] __attribute__((aligned(16)));
#pragma unroll
            for (int kk = 0; kk < 4; ++kk)
                *reinterpret_cast<float4*>(wf[kk]) =
                    *reinterpret_cast<const float4*>(&ws[(kq * 4 + kk) * NE + e0]);
            float xf[8][4] __attribute__((aligned(16)));
#pragma unroll
            for (int i = 0; i < 8; ++i)
                *reinterpret_cast<float4*>(xf[i]) =
                    *reinterpret_cast<const float4*>(&xs[(tg + 16 * i) * XS1 + kq * 4]);
            // k strictly ascending per (token,expert), FMA — matches BLAS chain
#pragma unroll
            for (int kk = 0; kk < 4; ++kk)
#pragma unroll
                for (int i = 0; i < 8; ++i)
#pragma unroll
                    for (int j = 0; j < 4; ++j)
                        acc[i][j] = fmaf(xf[i][kk], wf[kk][j], acc[i][j]);
        }
    }

    float* pt = part + ((size_t)b * N_TOKENS + g0) * NE;
#pragma unroll
    for (int i = 0; i < 8; ++i)
        *reinterpret_cast<float4*>(&pt[(tg + 16 * i) * NE + e0]) =
            *reinterpret_cast<float4*>(acc[i]);
}

// ------- Pass 2: fold 13 partials ascending (exact ref tree) + epilogue -------
// 2048 blocks x 4 waves; each wave = 2 tokens, lane = expert.
__global__ __launch_bounds__(256) void gate_pass2(
    const float* __restrict__ part, float* __restrict__ out)
{
    const int tid  = threadIdx.x;
    const int lane = tid & 63;
    const int wid  = tid >> 6;
    float* outI = out;
    float* outG = out + (size_t)N_TOKENS * TOPK;

#pragma unroll
    for (int tt = 0; tt < 2; ++tt) {
        const int g = blockIdx.x * 8 + wid * 2 + tt;

        // left-fold ascending b: ((B0+B1)+...)+B12  (0+B0 == B0 bit-exactly)
        float v = 0.0f;
#pragma unroll
        for (int bb = 0; bb < NCHUNK; ++bb)
            v += part[((size_t)bb * N_TOKENS + g) * NE + lane];

        float m = v;
#pragma unroll
        for (int off = 32; off; off >>= 1) m = fmaxf(m, __shfl_xor(m, off));
        float e = expf(v - m);
        float ssum = e;
#pragma unroll
        for (int off = 32; off; off >>= 1) ssum += __shfl_xor(ssum, off);
        float gte = e / ssum;

        // top-8 on logits (monotone == gate rank), ties -> lower index
        float curv = v;
        const int idx = lane;
        float myi = 0.0f, myg = 0.0f;
#pragma unroll
        for (int r = 0; r < TOPK; ++r) {
            float bv = curv;
            int   bi = idx;
#pragma unroll
            for (int off = 32; off; off >>= 1) {
                float ov = __shfl_xor(bv, off);
                int   oi = __shfl_xor(bi, off);
                if (ov > bv || (ov == bv && oi < bi)) { bv = ov; bi = oi; }
            }
            float wgv = __shfl(gte, bi);
            if (lane == r) { myi = (float)bi; myg = wgv; }
            if (idx == bi) curv = -INFINITY;
        }
        if (lane < TOPK) {
            outI[(size_t)g * TOPK + lane] = myi;
            outG[(size_t)g * TOPK + lane] = myg;
        }
    }
}

// ---------------- Fallback: verified single-pass round-5 kernel ----------------
#define TM 64
#define BK 64
#define XS_STRIDE 68
__global__ __launch_bounds__(256) void topk_gating_blas(
    const float* __restrict__ x, const float* __restrict__ w, float* __restrict__ out)
{
    __shared__ float xs[TM * XS_STRIDE];
    __shared__ float ws[BK * NE];

    const int tid = threadIdx.x;
    const int eg  = tid & 15;
    const int tg  = tid >> 4;
    const int e0  = eg * 4;
    const int t0  = tg * 4;
    const int bt0 = blockIdx.x * TM;

    float acc[4][4], tot[4][4];
#pragma unroll
    for (int i = 0; i < 4; ++i)
#pragma unroll
        for (int j = 0; j < 4; ++j) { acc[i][j] = 0.0f; tot[i][j] = 0.0f; }

    const float4* xg = reinterpret_cast<const float4*>(x);
    const float4* wg = reinterpret_cast<const float4*>(w);
    float4 xr[4], wr[4];

    auto load_step = [&](int k0) {
#pragma unroll
        for (int r = 0; r < 4; ++r) {
            int idx = tid + 256 * r;
            int T = idx >> 4, c = idx & 15;
            xr[r] = xg[(size_t)(bt0 + T) * (DIM / 4) + (k0 >> 2) + c];
            wr[r] = wg[(size_t)(k0 + T) * (NE / 4) + c];
        }
    };
    auto write_step = [&]() {
#pragma unroll
        for (int r = 0; r < 4; ++r) {
            int idx = tid + 256 * r;
            int T = idx >> 4, c = idx & 15;
            *reinterpret_cast<float4*>(&xs[T * XS_STRIDE + c * 4]) = xr[r];
            *reinterpret_cast<float4*>(&ws[T * NE + c * 4])        = wr[r];
        }
    };
    auto fold = [&]() {
#pragma unroll
        for (int i = 0; i < 4; ++i)
#pragma unroll
            for (int j = 0; j < 4; ++j) { tot[i][j] += acc[i][j]; acc[i][j] = 0.0f; }
    };

    load_step(0);
    for (int s = 0; s < DIM / BK; ++s) {
        __syncthreads();
        write_step();
        __syncthreads();
        if (s + 1 < DIM / BK) load_step((s + 1) * BK);
#pragma unroll
        for (int kq = 0; kq < 16; ++kq) {
            float xf[4][4], wf[4][4];
#pragma unroll
            for (int i = 0; i < 4; ++i)
                *reinterpret_cast<float4*>(xf[i]) =
                    *reinterpret_cast<const float4*>(&xs[(t0 + i) * XS_STRIDE + kq * 4]);
#pragma unroll
            for (int kk = 0; kk < 4; ++kk)
                *reinterpret_cast<float4*>(wf[kk]) =
                    *reinterpret_cast<const float4*>(&ws[(kq * 4 + kk) * NE + e0]);
#pragma unroll
            for (int kk = 0; kk < 4; ++kk)
#pragma unroll
                for (int i = 0; i < 4; ++i)
#pragma unroll
                    for (int j = 0; j < 4; ++j)
                        acc[i][j] = fmaf(xf[i][kk], wf[kk][j], acc[i][j]);
            if (kq == 7 && s == 59) fold();
        }
        if ((s % 5) == 4 && s <= 54) fold();
    }
    fold();

    __syncthreads();
#pragma unroll
    for (int i = 0; i < 4; ++i)
        *reinterpret_cast<float4*>(&xs[(t0 + i) * XS_STRIDE + e0]) =
            *reinterpret_cast<float4*>(tot[i]);
    __syncthreads();

    const int lane = tid & 63;
    const int wid  = tid >> 6;
    float* outI = out;
    float* outG = out + (size_t)N_TOKENS * TOPK;

    for (int tt = 0; tt < 16; ++tt) {
        const int t = wid * 16 + tt;
        float v = xs[t * XS_STRIDE + lane];
        float m = v;
#pragma unroll
        for (int off = 32; off; off >>= 1) m = fmaxf(m, __shfl_xor(m, off));
        float e = expf(v - m);
        float ssum = e;
#pragma unroll
        for (int off = 32; off; off >>= 1) ssum += __shfl_xor(ssum, off);
        float g = e / ssum;

        float curv = v;
        const int idx = lane;
        float myi = 0.0f, myg = 0.0f;
#pragma unroll
        for (int r = 0; r < TOPK; ++r) {
            float bv = curv;
            int   bi = idx;
#pragma unroll
            for (int off = 32; off; off >>= 1) {
                float ov = __shfl_xor(bv, off);
                int   oi = __shfl_xor(bi, off);
                if (ov > bv || (ov == bv && oi < bi)) { bv = ov; bi = oi; }
            }
            float wgv = __shfl(g, bi);
            if (lane == r) { myi = (float)bi; myg = wgv; }
            if (idx == bi) curv = -INFINITY;
        }
        const int gt = bt0 + t;
        if (lane < TOPK) {
            outI[(size_t)gt * TOPK + lane] = myi;
            outG[(size_t)gt * TOPK + lane] = myg;
        }
    }
}

extern "C" void kernel_launch(void* const* d_in, const int* in_sizes, int n_in,
                              void* d_out, int out_size, void* d_ws, size_t ws_size,
                              hipStream_t stream) {
    const float* x = (const float*)d_in[0];
    const float* w = (const float*)d_in[1];
    float* out = (float*)d_out;
    const size_t needed = (size_t)NCHUNK * N_TOKENS * NE * sizeof(float);  // 54.5 MB
    if (ws_size >= needed) {
        float* part = (float*)d_ws;
        gate_pass1<<<dim3(NT1, NCHUNK), dim3(256), 0, stream>>>(x, w, part);
        gate_pass2<<<dim3(N_TOKENS / 8), dim3(256), 0, stream>>>(part, out);
    } else {
        topk_gating_blas<<<dim3(N_TOKENS / TM), dim3(256), 0, stream>>>(x, w, out);
    }
}

// Round 8
// 215.899 us; speedup vs baseline: 1.6055x; 1.0920x over previous
//
#include <hip/hip_runtime.h>
#include <hip/hip_bf16.h>
#include <math.h>

#define N_TOKENS 16384
#define DIM      4096
#define NE       64
#define TOPK     8
#define NCHUNK   13     // OpenBLAS Kc blocks: [320 x 11, 288, 288]
#define TM1      128    // pass1 tokens per block
#define XS1      36     // pass1 x-row stride (32 + 4 pad)
#define NT1      (N_TOKENS / TM1)   // 128 token tiles

// ---------------- Pass 1: one OpenBLAS K-chunk per block.y ----------------
// part layout: part[b][token][expert], b = 0..12
// NOTE: plain __launch_bounds__(256) — rounds 6/7 proved that a min-waves
// constraint (reported VGPR 40/64 vs ~130 live) forces scratch spills
// (WRITE_SIZE ~400MB) and pins VALUBusy at the stall floor.
__global__ __launch_bounds__(256) void gate_pass1(
    const float* __restrict__ x, const float* __restrict__ w, float* __restrict__ part)
{
    __shared__ float xs[TM1 * XS1];  // 18432 B
    __shared__ float ws[32 * NE];    //  8192 B

    const int tid = threadIdx.x;
    const int eg  = tid & 15;        // expert group (4 experts)
    const int tg  = tid >> 4;        // token base 0..15
    const int e0  = eg * 4;
    const int g0  = blockIdx.x * TM1;
    const int b   = blockIdx.y;
    const int kstart = (b < 12) ? 320 * b : 3808;
    const int nsteps = (b < 11) ? 10 : 9;          // 320 = 10*32, 288 = 9*32

    float acc[8][4];
#pragma unroll
    for (int i = 0; i < 8; ++i)
#pragma unroll
        for (int j = 0; j < 4; ++j) acc[i][j] = 0.0f;

    const float4* xg = reinterpret_cast<const float4*>(x);
    const float4* wg = reinterpret_cast<const float4*>(w);
    float4 xr[4], wr[2];

    auto load_step = [&](int k0) {
#pragma unroll
        for (int r = 0; r < 4; ++r) {             // x: 128 rows x 8 float4
            int idx = tid + 256 * r;
            int row = idx >> 3, col = idx & 7;
            xr[r] = xg[(size_t)(g0 + row) * (DIM / 4) + (k0 >> 2) + col];
        }
#pragma unroll
        for (int r = 0; r < 2; ++r) {             // w: 32 rows x 16 float4
            int idx = tid + 256 * r;
            int row = idx >> 4, col = idx & 15;
            wr[r] = wg[(size_t)(k0 + row) * (NE / 4) + col];
        }
    };
    auto write_step = [&]() {
#pragma unroll
        for (int r = 0; r < 4; ++r) {
            int idx = tid + 256 * r;
            int row = idx >> 3, col = idx & 7;
            *reinterpret_cast<float4*>(&xs[row * XS1 + col * 4]) = xr[r];
        }
#pragma unroll
        for (int r = 0; r < 2; ++r) {
            int idx = tid + 256 * r;
            int row = idx >> 4, col = idx & 15;
            *reinterpret_cast<float4*>(&ws[row * NE + col * 4]) = wr[r];
        }
    };

    load_step(kstart);
    for (int s = 0; s < nsteps; ++s) {
        __syncthreads();
        write_step();
        __syncthreads();
        if (s + 1 < nsteps) load_step(kstart + 32 * (s + 1));

#pragma unroll
        for (int kq = 0; kq < 8; ++kq) {
            float wf[4][4];
#pragma unroll
            for (int kk = 0; kk < 4; ++kk)
                *reinterpret_cast<float4*>(wf[kk]) =
                    *reinterpret_cast<const float4*>(&ws[(kq * 4 + kk) * NE + e0]);
            // One x-row at a time: small live set, no spills.
            // Per (token i, expert j): kk ascends 0..3 -> k strictly ascending.
#pragma unroll
            for (int i = 0; i < 8; ++i) {
                float xv[4];
                *reinterpret_cast<float4*>(xv) =
                    *reinterpret_cast<const float4*>(&xs[(tg + 16 * i) * XS1 + kq * 4]);
#pragma unroll
                for (int kk = 0; kk < 4; ++kk)
#pragma unroll
                    for (int j = 0; j < 4; ++j)
                        acc[i][j] = fmaf(xv[kk], wf[kk][j], acc[i][j]);
            }
        }
    }

    float* pt = part + ((size_t)b * N_TOKENS + g0) * NE;
#pragma unroll
    for (int i = 0; i < 8; ++i)
        *reinterpret_cast<float4*>(&pt[(tg + 16 * i) * NE + e0]) =
            *reinterpret_cast<float4*>(acc[i]);
}

// ------- Pass 2: fold 13 partials ascending (exact ref tree) + epilogue -------
// 2048 blocks x 4 waves; each wave = 2 tokens, lane = expert.
__global__ __launch_bounds__(256) void gate_pass2(
    const float* __restrict__ part, float* __restrict__ out)
{
    const int tid  = threadIdx.x;
    const int lane = tid & 63;
    const int wid  = tid >> 6;
    float* outI = out;
    float* outG = out + (size_t)N_TOKENS * TOPK;

#pragma unroll
    for (int tt = 0; tt < 2; ++tt) {
        const int g = blockIdx.x * 8 + wid * 2 + tt;

        // left-fold ascending b: ((B0+B1)+...)+B12  (0+B0 == B0 bit-exactly)
        float v = 0.0f;
#pragma unroll
        for (int bb = 0; bb < NCHUNK; ++bb)
            v += part[((size_t)bb * N_TOKENS + g) * NE + lane];

        float m = v;
#pragma unroll
        for (int off = 32; off; off >>= 1) m = fmaxf(m, __shfl_xor(m, off));
        float e = expf(v - m);
        float ssum = e;
#pragma unroll
        for (int off = 32; off; off >>= 1) ssum += __shfl_xor(ssum, off);
        float gte = e / ssum;

        // top-8 on logits (monotone == gate rank), ties -> lower index
        float curv = v;
        const int idx = lane;
        float myi = 0.0f, myg = 0.0f;
#pragma unroll
        for (int r = 0; r < TOPK; ++r) {
            float bv = curv;
            int   bi = idx;
#pragma unroll
            for (int off = 32; off; off >>= 1) {
                float ov = __shfl_xor(bv, off);
                int   oi = __shfl_xor(bi, off);
                if (ov > bv || (ov == bv && oi < bi)) { bv = ov; bi = oi; }
            }
            float wgv = __shfl(gte, bi);
            if (lane == r) { myi = (float)bi; myg = wgv; }
            if (idx == bi) curv = -INFINITY;
        }
        if (lane < TOPK) {
            outI[(size_t)g * TOPK + lane] = myi;
            outG[(size_t)g * TOPK + lane] = myg;
        }
    }
}

// ---------------- Fallback: verified single-pass round-5 kernel ----------------
#define TM 64
#define BK 64
#define XS_STRIDE 68
__global__ __launch_bounds__(256) void topk_gating_blas(
    const float* __restrict__ x, const float* __restrict__ w, float* __restrict__ out)
{
    __shared__ float xs[TM * XS_STRIDE];
    __shared__ float ws[BK * NE];

    const int tid = threadIdx.x;
    const int eg  = tid & 15;
    const int tg  = tid >> 4;
    const int e0  = eg * 4;
    const int t0  = tg * 4;
    const int bt0 = blockIdx.x * TM;

    float acc[4][4], tot[4][4];
#pragma unroll
    for (int i = 0; i < 4; ++i)
#pragma unroll
        for (int j = 0; j < 4; ++j) { acc[i][j] = 0.0f; tot[i][j] = 0.0f; }

    const float4* xg = reinterpret_cast<const float4*>(x);
    const float4* wg = reinterpret_cast<const float4*>(w);
    float4 xr[4], wr[4];

    auto load_step = [&](int k0) {
#pragma unroll
        for (int r = 0; r < 4; ++r) {
            int idx = tid + 256 * r;
            int T = idx >> 4, c = idx & 15;
            xr[r] = xg[(size_t)(bt0 + T) * (DIM / 4) + (k0 >> 2) + c];
            wr[r] = wg[(size_t)(k0 + T) * (NE / 4) + c];
        }
    };
    auto write_step = [&]() {
#pragma unroll
        for (int r = 0; r < 4; ++r) {
            int idx = tid + 256 * r;
            int T = idx >> 4, c = idx & 15;
            *reinterpret_cast<float4*>(&xs[T * XS_STRIDE + c * 4]) = xr[r];
            *reinterpret_cast<float4*>(&ws[T * NE + c * 4])        = wr[r];
        }
    };
    auto fold = [&]() {
#pragma unroll
        for (int i = 0; i < 4; ++i)
#pragma unroll
            for (int j = 0; j < 4; ++j) { tot[i][j] += acc[i][j]; acc[i][j] = 0.0f; }
    };

    load_step(0);
    for (int s = 0; s < DIM / BK; ++s) {
        __syncthreads();
        write_step();
        __syncthreads();
        if (s + 1 < DIM / BK) load_step((s + 1) * BK);
#pragma unroll
        for (int kq = 0; kq < 16; ++kq) {
            float xf[4][4], wf[4][4];
#pragma unroll
            for (int i = 0; i < 4; ++i)
                *reinterpret_cast<float4*>(xf[i]) =
                    *reinterpret_cast<const float4*>(&xs[(t0 + i) * XS_STRIDE + kq * 4]);
#pragma unroll
            for (int kk = 0; kk < 4; ++kk)
                *reinterpret_cast<float4*>(wf[kk]) =
                    *reinterpret_cast<const float4*>(&ws[(kq * 4 + kk) * NE + e0]);
#pragma unroll
            for (int kk = 0; kk < 4; ++kk)
#pragma unroll
                for (int i = 0; i < 4; ++i)
#pragma unroll
                    for (int j = 0; j < 4; ++j)
                        acc[i][j] = fmaf(xf[i][kk], wf[kk][j], acc[i][j]);
            if (kq == 7 && s == 59) fold();
        }
        if ((s % 5) == 4 && s <= 54) fold();
    }
    fold();

    __syncthreads();
#pragma unroll
    for (int i = 0; i < 4; ++i)
        *reinterpret_cast<float4*>(&xs[(t0 + i) * XS_STRIDE + e0]) =
            *reinterpret_cast<float4*>(tot[i]);
    __syncthreads();

    const int lane = tid & 63;
    const int wid  = tid >> 6;
    float* outI = out;
    float* outG = out + (size_t)N_TOKENS * TOPK;

    for (int tt = 0; tt < 16; ++tt) {
        const int t = wid * 16 + tt;
        float v = xs[t * XS_STRIDE + lane];
        float m = v;
#pragma unroll
        for (int off = 32; off; off >>= 1) m = fmaxf(m, __shfl_xor(m, off));
        float e = expf(v - m);
        float ssum = e;
#pragma unroll
        for (int off = 32; off; off >>= 1) ssum += __shfl_xor(ssum, off);
        float g = e / ssum;

        float curv = v;
        const int idx = lane;
        float myi = 0.0f, myg = 0.0f;
#pragma unroll
        for (int r = 0; r < TOPK; ++r) {
            float bv = curv;
            int   bi = idx;
#pragma unroll
            for (int off = 32; off; off >>= 1) {
                float ov = __shfl_xor(bv, off);
                int   oi = __shfl_xor(bi, off);
                if (ov > bv || (ov == bv && oi < bi)) { bv = ov; bi = oi; }
            }
            float wgv = __shfl(g, bi);
            if (lane == r) { myi = (float)bi; myg = wgv; }
            if (idx == bi) curv = -INFINITY;
        }
        const int gt = bt0 + t;
        if (lane < TOPK) {
            outI[(size_t)gt * TOPK + lane] = myi;
            outG[(size_t)gt * TOPK + lane] = myg;
        }
    }
}

extern "C" void kernel_launch(void* const* d_in, const int* in_sizes, int n_in,
                              void* d_out, int out_size, void* d_ws, size_t ws_size,
                              hipStream_t stream) {
    const float* x = (const float*)d_in[0];
    const float* w = (const float*)d_in[1];
    float* out = (float*)d_out;
    const size_t needed = (size_t)NCHUNK * N_TOKENS * NE * sizeof(float);  // 54.5 MB
    if (ws_size >= needed) {
        float* part = (float*)d_ws;
        gate_pass1<<<dim3(NT1, NCHUNK), dim3(256), 0, stream>>>(x, w, part);
        gate_pass2<<<dim3(N_TOKENS / 8), dim3(256), 0, stream>>>(part, out);
    } else {
        topk_gating_blas<<<dim3(N_TOKENS / TM), dim3(256), 0, stream>>>(x, w, out);
    }
}

// Round 9
// 208.860 us; speedup vs baseline: 1.6596x; 1.0337x over previous
//
#include <hip/hip_runtime.h>
#include <hip/hip_bf16.h>
#include <math.h>

#define N_TOKENS 16384
#define DIM      4096
#define NE       64
#define TOPK     8
#define NCHUNK   13     // OpenBLAS Kc blocks: [320 x 11, 288, 288]
#define TM1      256    // pass1 tokens per block
#define XS1      36     // pass1 x-row stride (32 + 4 pad)
#define NT1      (N_TOKENS / TM1)   // 64 token tiles

// ---------------- Pass 1: one OpenBLAS K-chunk per block.y ----------------
// part[b][token][expert]. Micro-tile 8 tok x 8 exp per thread (1.0 B/FMA LDS).
// waves_per_eu(2,3): rounds 6-8 showed the LDS-derived default occupancy
// target caps VGPRs (40/64/68 vs ~140 live) and forces scratch spills
// (WRITE_SIZE 330-430MB). Pin target 3 waves/SIMD (cap ~170), floor 2 (256).
__global__ __launch_bounds__(256)
__attribute__((amdgpu_waves_per_eu(2, 3)))
void gate_pass1(
    const float* __restrict__ x, const float* __restrict__ w, float* __restrict__ part)
{
    __shared__ float xs[TM1 * XS1];  // 36864 B
    __shared__ float ws[32 * NE];    //  8192 B

    const int tid = threadIdx.x;
    const int eg  = tid & 7;         // expert group (8 experts)
    const int tg  = tid >> 3;        // token base 0..31
    const int e0  = eg * 8;
    const int g0  = blockIdx.x * TM1;
    const int b   = blockIdx.y;
    const int kstart = (b < 12) ? 320 * b : 3808;
    const int nsteps = (b < 11) ? 10 : 9;          // 320 = 10*32, 288 = 9*32

    float acc[8][8];
#pragma unroll
    for (int i = 0; i < 8; ++i)
#pragma unroll
        for (int j = 0; j < 8; ++j) acc[i][j] = 0.0f;

    const float4* xg = reinterpret_cast<const float4*>(x);
    const float4* wg = reinterpret_cast<const float4*>(w);
    float4 xr[8], wr[2];

    auto load_step = [&](int k0) {
#pragma unroll
        for (int r = 0; r < 8; ++r) {             // x: 256 rows x 8 float4
            int idx = tid + 256 * r;
            int row = idx >> 3, col = idx & 7;
            xr[r] = xg[(size_t)(g0 + row) * (DIM / 4) + (k0 >> 2) + col];
        }
#pragma unroll
        for (int r = 0; r < 2; ++r) {             // w: 32 rows x 16 float4
            int idx = tid + 256 * r;
            int row = idx >> 4, col = idx & 15;
            wr[r] = wg[(size_t)(k0 + row) * (NE / 4) + col];
        }
    };
    auto write_step = [&]() {
#pragma unroll
        for (int r = 0; r < 8; ++r) {
            int idx = tid + 256 * r;
            int row = idx >> 3, col = idx & 7;
            *reinterpret_cast<float4*>(&xs[row * XS1 + col * 4]) = xr[r];
        }
#pragma unroll
        for (int r = 0; r < 2; ++r) {
            int idx = tid + 256 * r;
            int row = idx >> 4, col = idx & 15;
            *reinterpret_cast<float4*>(&ws[row * NE + col * 4]) = wr[r];
        }
    };

    load_step(kstart);
    for (int s = 0; s < nsteps; ++s) {
        __syncthreads();
        write_step();
        __syncthreads();
        if (s + 1 < nsteps) load_step(kstart + 32 * (s + 1));

#pragma unroll
        for (int kq = 0; kq < 8; ++kq) {
            float wf[4][8];   // 4 k-values x 8 experts
#pragma unroll
            for (int kk = 0; kk < 4; ++kk) {
                *reinterpret_cast<float4*>(&wf[kk][0]) =
                    *reinterpret_cast<const float4*>(&ws[(kq * 4 + kk) * NE + e0]);
                *reinterpret_cast<float4*>(&wf[kk][4]) =
                    *reinterpret_cast<const float4*>(&ws[(kq * 4 + kk) * NE + e0 + 4]);
            }
            // Per (token i, expert j): kk ascends 0..3, kq ascends, steps ascend
            // -> strictly ascending k within the chunk (exact BLAS chain).
#pragma unroll
            for (int i = 0; i < 8; ++i) {
                float xv[4];
                *reinterpret_cast<float4*>(xv) =
                    *reinterpret_cast<const float4*>(&xs[(tg + 32 * i) * XS1 + kq * 4]);
#pragma unroll
                for (int kk = 0; kk < 4; ++kk)
#pragma unroll
                    for (int j = 0; j < 8; ++j)
                        acc[i][j] = fmaf(xv[kk], wf[kk][j], acc[i][j]);
            }
        }
    }

    float* pt = part + ((size_t)b * N_TOKENS + g0) * NE;
#pragma unroll
    for (int i = 0; i < 8; ++i) {
        *reinterpret_cast<float4*>(&pt[(tg + 32 * i) * NE + e0]) =
            *reinterpret_cast<float4*>(&acc[i][0]);
        *reinterpret_cast<float4*>(&pt[(tg + 32 * i) * NE + e0 + 4]) =
            *reinterpret_cast<float4*>(&acc[i][4]);
    }
}

// ------- Pass 2: fold 13 partials ascending (exact ref tree) + epilogue -------
// 2048 blocks x 4 waves; each wave = 2 tokens, lane = expert.
__global__ __launch_bounds__(256) void gate_pass2(
    const float* __restrict__ part, float* __restrict__ out)
{
    const int tid  = threadIdx.x;
    const int lane = tid & 63;
    const int wid  = tid >> 6;
    float* outI = out;
    float* outG = out + (size_t)N_TOKENS * TOPK;

#pragma unroll
    for (int tt = 0; tt < 2; ++tt) {
        const int g = blockIdx.x * 8 + wid * 2 + tt;

        // left-fold ascending b: ((B0+B1)+...)+B12  (0+B0 == B0 bit-exactly)
        float v = 0.0f;
#pragma unroll
        for (int bb = 0; bb < NCHUNK; ++bb)
            v += part[((size_t)bb * N_TOKENS + g) * NE + lane];

        float m = v;
#pragma unroll
        for (int off = 32; off; off >>= 1) m = fmaxf(m, __shfl_xor(m, off));
        float e = expf(v - m);
        float ssum = e;
#pragma unroll
        for (int off = 32; off; off >>= 1) ssum += __shfl_xor(ssum, off);
        float gte = e / ssum;

        // top-8 on logits (monotone == gate rank), ties -> lower index
        float curv = v;
        const int idx = lane;
        float myi = 0.0f, myg = 0.0f;
#pragma unroll
        for (int r = 0; r < TOPK; ++r) {
            float bv = curv;
            int   bi = idx;
#pragma unroll
            for (int off = 32; off; off >>= 1) {
                float ov = __shfl_xor(bv, off);
                int   oi = __shfl_xor(bi, off);
                if (ov > bv || (ov == bv && oi < bi)) { bv = ov; bi = oi; }
            }
            float wgv = __shfl(gte, bi);
            if (lane == r) { myi = (float)bi; myg = wgv; }
            if (idx == bi) curv = -INFINITY;
        }
        if (lane < TOPK) {
            outI[(size_t)g * TOPK + lane] = myi;
            outG[(size_t)g * TOPK + lane] = myg;
        }
    }
}

// ---------------- Fallback: verified single-pass round-5 kernel ----------------
#define TM 64
#define BK 64
#define XS_STRIDE 68
__global__ __launch_bounds__(256) void topk_gating_blas(
    const float* __restrict__ x, const float* __restrict__ w, float* __restrict__ out)
{
    __shared__ float xs[TM * XS_STRIDE];
    __shared__ float ws[BK * NE];

    const int tid = threadIdx.x;
    const int eg  = tid & 15;
    const int tg  = tid >> 4;
    const int e0  = eg * 4;
    const int t0  = tg * 4;
    const int bt0 = blockIdx.x * TM;

    float acc[4][4], tot[4][4];
#pragma unroll
    for (int i = 0; i < 4; ++i)
#pragma unroll
        for (int j = 0; j < 4; ++j) { acc[i][j] = 0.0f; tot[i][j] = 0.0f; }

    const float4* xg = reinterpret_cast<const float4*>(x);
    const float4* wg = reinterpret_cast<const float4*>(w);
    float4 xr[4], wr[4];

    auto load_step = [&](int k0) {
#pragma unroll
        for (int r = 0; r < 4; ++r) {
            int idx = tid + 256 * r;
            int T = idx >> 4, c = idx & 15;
            xr[r] = xg[(size_t)(bt0 + T) * (DIM / 4) + (k0 >> 2) + c];
            wr[r] = wg[(size_t)(k0 + T) * (NE / 4) + c];
        }
    };
    auto write_step = [&]() {
#pragma unroll
        for (int r = 0; r < 4; ++r) {
            int idx = tid + 256 * r;
            int T = idx >> 4, c = idx & 15;
            *reinterpret_cast<float4*>(&xs[T * XS_STRIDE + c * 4]) = xr[r];
            *reinterpret_cast<float4*>(&ws[T * NE + c * 4])        = wr[r];
        }
    };
    auto fold = [&]() {
#pragma unroll
        for (int i = 0; i < 4; ++i)
#pragma unroll
            for (int j = 0; j < 4; ++j) { tot[i][j] += acc[i][j]; acc[i][j] = 0.0f; }
    };

    load_step(0);
    for (int s = 0; s < DIM / BK; ++s) {
        __syncthreads();
        write_step();
        __syncthreads();
        if (s + 1 < DIM / BK) load_step((s + 1) * BK);
#pragma unroll
        for (int kq = 0; kq < 16; ++kq) {
            float xf[4][4], wf[4][4];
#pragma unroll
            for (int i = 0; i < 4; ++i)
                *reinterpret_cast<float4*>(xf[i]) =
                    *reinterpret_cast<const float4*>(&xs[(t0 + i) * XS_STRIDE + kq * 4]);
#pragma unroll
            for (int kk = 0; kk < 4; ++kk)
                *reinterpret_cast<float4*>(wf[kk]) =
                    *reinterpret_cast<const float4*>(&ws[(kq * 4 + kk) * NE + e0]);
#pragma unroll
            for (int kk = 0; kk < 4; ++kk)
#pragma unroll
                for (int i = 0; i < 4; ++i)
#pragma unroll
                    for (int j = 0; j < 4; ++j)
                        acc[i][j] = fmaf(xf[i][kk], wf[kk][j], acc[i][j]);
            if (kq == 7 && s == 59) fold();
        }
        if ((s % 5) == 4 && s <= 54) fold();
    }
    fold();

    __syncthreads();
#pragma unroll
    for (int i = 0; i < 4; ++i)
        *reinterpret_cast<float4*>(&xs[(t0 + i) * XS_STRIDE + e0]) =
            *reinterpret_cast<float4*>(tot[i]);
    __syncthreads();

    const int lane = tid & 63;
    const int wid  = tid >> 6;
    float* outI = out;
    float* outG = out + (size_t)N_TOKENS * TOPK;

    for (int tt = 0; tt < 16; ++tt) {
        const int t = wid * 16 + tt;
        float v = xs[t * XS_STRIDE + lane];
        float m = v;
#pragma unroll
        for (int off = 32; off; off >>= 1) m = fmaxf(m, __shfl_xor(m, off));
        float e = expf(v - m);
        float ssum = e;
#pragma unroll
        for (int off = 32; off; off >>= 1) ssum += __shfl_xor(ssum, off);
        float g = e / ssum;

        float curv = v;
        const int idx = lane;
        float myi = 0.0f, myg = 0.0f;
#pragma unroll
        for (int r = 0; r < TOPK; ++r) {
            float bv = curv;
            int   bi = idx;
#pragma unroll
            for (int off = 32; off; off >>= 1) {
                float ov = __shfl_xor(bv, off);
                int   oi = __shfl_xor(bi, off);
                if (ov > bv || (ov == bv && oi < bi)) { bv = ov; bi = oi; }
            }
            float wgv = __shfl(g, bi);
            if (lane == r) { myi = (float)bi; myg = wgv; }
            if (idx == bi) curv = -INFINITY;
        }
        const int gt = bt0 + t;
        if (lane < TOPK) {
            outI[(size_t)gt * TOPK + lane] = myi;
            outG[(size_t)gt * TOPK + lane] = myg;
        }
    }
}

extern "C" void kernel_launch(void* const* d_in, const int* in_sizes, int n_in,
                              void* d_out, int out_size, void* d_ws, size_t ws_size,
                              hipStream_t stream) {
    const float* x = (const float*)d_in[0];
    const float* w = (const float*)d_in[1];
    float* out = (float*)d_out;
    const size_t needed = (size_t)NCHUNK * N_TOKENS * NE * sizeof(float);  // 54.5 MB
    if (ws_size >= needed) {
        float* part = (float*)d_ws;
        gate_pass1<<<dim3(NT1, NCHUNK), dim3(256), 0, stream>>>(x, w, part);
        gate_pass2<<<dim3(N_TOKENS / 8), dim3(256), 0, stream>>>(part, out);
    } else {
        topk_gating_blas<<<dim3(N_TOKENS / TM), dim3(256), 0, stream>>>(x, w, out);
    }
}

// Round 10
// 193.546 us; speedup vs baseline: 1.7909x; 1.0791x over previous
//
#include <hip/hip_runtime.h>
#include <hip/hip_bf16.h>
#include <math.h>

#define N_TOKENS 16384
#define DIM      4096
#define NE       64
#define TOPK     8
#define NCHUNK   13     // OpenBLAS Kc blocks: [320 x 11, 288, 288]
#define TM1      256    // pass1 tokens per block
#define NT1      (N_TOKENS / TM1)   // 64 token tiles

// HBM -> LDS direct (no VGPR round-trip). LDS dest must be wave-uniform.
__device__ __forceinline__ void gld16(const float* g, float* l) {
    __builtin_amdgcn_global_load_lds(
        (const __attribute__((address_space(1))) void*)g,
        (__attribute__((address_space(3))) void*)l, 16, 0, 0);
}

// ---------------- Pass 1: one OpenBLAS K-chunk per block.y ----------------
// part[b][token][expert]. Micro-tile 8 tok x 8 exp per thread (1.0 B/FMA LDS).
// Staging via global_load_lds: rounds 6-9 showed reg-staged prefetch keeps
// 40 VGPRs live across compute -> allocator spills (WRITE_SIZE 250-430MB).
// x tile: linear [256][32] rows (128B), XOR-swizzle c4^=(row&7) applied by
// pre-swizzling the per-lane GLOBAL source (LDS dest stays linear, m173);
// swizzled ds_read puts the 8 rows/wave on 8 distinct bank groups.
__global__ __launch_bounds__(256) void gate_pass1(
    const float* __restrict__ x, const float* __restrict__ w, float* __restrict__ part)
{
    __shared__ float xs[2][TM1 * 32];  // 2 x 32 KB
    __shared__ float ws[2][32 * NE];   // 2 x  8 KB

    const int tid = threadIdx.x;
    const int lane = tid & 63;
    const int wid  = tid >> 6;
    const int eg  = tid & 7;         // expert group (8 experts)
    const int tg  = tid >> 3;        // token base 0..31
    const int e0  = eg * 8;
    const int g0  = blockIdx.x * TM1;
    const int b   = blockIdx.y;
    const int kstart = (b < 12) ? 320 * b : 3808;
    const int nsteps = (b < 11) ? 10 : 9;          // 320 = 10*32, 288 = 9*32

    float acc[8][8];
#pragma unroll
    for (int i = 0; i < 8; ++i)
#pragma unroll
        for (int j = 0; j < 8; ++j) acc[i][j] = 0.0f;

    // Per-lane source geometry (constant across calls):
    const int rsub = lane >> 3;            // row within an 8-row call group
    const int c4s  = (lane & 7) ^ rsub;    // pre-swizzled float4 column of x
    // x: 8 calls/wave, call q covers rows (wid*8+q)*8 .. +7
    // w: 2 calls/wave, call q covers a contiguous 1KB of the 8KB tile
    auto stage = [&](int buf, int k0) {
#pragma unroll
        for (int q = 0; q < 8; ++q) {
            const int rowbase = (wid * 8 + q) * 8;
            const float* src = x + (size_t)(g0 + rowbase + rsub) * DIM + k0 + c4s * 4;
            gld16(src, &xs[buf][rowbase * 32]);          // wave-uniform dest
        }
#pragma unroll
        for (int q = 0; q < 2; ++q) {
            const int off = (wid * 2 + q) * 256;         // floats
            const float* src = w + (size_t)k0 * NE + off + lane * 4;
            gld16(src, &ws[buf][off]);                   // wave-uniform dest
        }
    };

    stage(0, kstart);
    int cur = 0;
    for (int s = 0; s < nsteps; ++s) {
        __syncthreads();   // compiler drains vmcnt(0): buf[cur] ready; prev compute done
        if (s + 1 < nsteps) stage(cur ^ 1, kstart + 32 * (s + 1));

        const int tg7 = tg & 7;
#pragma unroll
        for (int kq = 0; kq < 8; ++kq) {
            float wf[4][8];   // 4 k-values x 8 experts
#pragma unroll
            for (int kk = 0; kk < 4; ++kk) {
                *reinterpret_cast<float4*>(&wf[kk][0]) =
                    *reinterpret_cast<const float4*>(&ws[cur][(kq * 4 + kk) * NE + e0]);
                *reinterpret_cast<float4*>(&wf[kk][4]) =
                    *reinterpret_cast<const float4*>(&ws[cur][(kq * 4 + kk) * NE + e0 + 4]);
            }
            const int kqs = (kq ^ tg7) * 4;   // un-swizzle on read
            // Per (token i, expert j): kk 0..3, kq 0..7, steps ascend
            // -> strictly ascending k within the chunk (exact BLAS chain).
#pragma unroll
            for (int i = 0; i < 8; ++i) {
                float xv[4];
                *reinterpret_cast<float4*>(xv) =
                    *reinterpret_cast<const float4*>(&xs[cur][(tg + 32 * i) * 32 + kqs]);
#pragma unroll
                for (int kk = 0; kk < 4; ++kk)
#pragma unroll
                    for (int j = 0; j < 8; ++j)
                        acc[i][j] = fmaf(xv[kk], wf[kk][j], acc[i][j]);
            }
        }
        cur ^= 1;
    }

    float* pt = part + ((size_t)b * N_TOKENS + g0) * NE;
#pragma unroll
    for (int i = 0; i < 8; ++i) {
        *reinterpret_cast<float4*>(&pt[(tg + 32 * i) * NE + e0]) =
            *reinterpret_cast<float4*>(&acc[i][0]);
        *reinterpret_cast<float4*>(&pt[(tg + 32 * i) * NE + e0 + 4]) =
            *reinterpret_cast<float4*>(&acc[i][4]);
    }
}

// ------- Pass 2: fold 13 partials ascending (exact ref tree) + epilogue -------
// 2048 blocks x 4 waves; each wave = 2 tokens, lane = expert.
__global__ __launch_bounds__(256) void gate_pass2(
    const float* __restrict__ part, float* __restrict__ out)
{
    const int tid  = threadIdx.x;
    const int lane = tid & 63;
    const int wid  = tid >> 6;
    float* outI = out;
    float* outG = out + (size_t)N_TOKENS * TOPK;

#pragma unroll
    for (int tt = 0; tt < 2; ++tt) {
        const int g = blockIdx.x * 8 + wid * 2 + tt;

        // left-fold ascending b: ((B0+B1)+...)+B12  (0+B0 == B0 bit-exactly)
        float v = 0.0f;
#pragma unroll
        for (int bb = 0; bb < NCHUNK; ++bb)
            v += part[((size_t)bb * N_TOKENS + g) * NE + lane];

        float m = v;
#pragma unroll
        for (int off = 32; off; off >>= 1) m = fmaxf(m, __shfl_xor(m, off));
        float e = expf(v - m);
        float ssum = e;
#pragma unroll
        for (int off = 32; off; off >>= 1) ssum += __shfl_xor(ssum, off);
        float gte = e / ssum;

        // top-8 on logits (monotone == gate rank), ties -> lower index
        float curv = v;
        const int idx = lane;
        float myi = 0.0f, myg = 0.0f;
#pragma unroll
        for (int r = 0; r < TOPK; ++r) {
            float bv = curv;
            int   bi = idx;
#pragma unroll
            for (int off = 32; off; off >>= 1) {
                float ov = __shfl_xor(bv, off);
                int   oi = __shfl_xor(bi, off);
                if (ov > bv || (ov == bv && oi < bi)) { bv = ov; bi = oi; }
            }
            float wgv = __shfl(gte, bi);
            if (lane == r) { myi = (float)bi; myg = wgv; }
            if (idx == bi) curv = -INFINITY;
        }
        if (lane < TOPK) {
            outI[(size_t)g * TOPK + lane] = myi;
            outG[(size_t)g * TOPK + lane] = myg;
        }
    }
}

// ---------------- Fallback: verified single-pass round-5 kernel ----------------
#define TM 64
#define BK 64
#define XS_STRIDE 68
__global__ __launch_bounds__(256) void topk_gating_blas(
    const float* __restrict__ x, const float* __restrict__ w, float* __restrict__ out)
{
    __shared__ float xs[TM * XS_STRIDE];
    __shared__ float ws[BK * NE];

    const int tid = threadIdx.x;
    const int eg  = tid & 15;
    const int tg  = tid >> 4;
    const int e0  = eg * 4;
    const int t0  = tg * 4;
    const int bt0 = blockIdx.x * TM;

    float acc[4][4], tot[4][4];
#pragma unroll
    for (int i = 0; i < 4; ++i)
#pragma unroll
        for (int j = 0; j < 4; ++j) { acc[i][j] = 0.0f; tot[i][j] = 0.0f; }

    const float4* xg = reinterpret_cast<const float4*>(x);
    const float4* wg = reinterpret_cast<const float4*>(w);
    float4 xr[4], wr[4];

    auto load_step = [&](int k0) {
#pragma unroll
        for (int r = 0; r < 4; ++r) {
            int idx = tid + 256 * r;
            int T = idx >> 4, c = idx & 15;
            xr[r] = xg[(size_t)(bt0 + T) * (DIM / 4) + (k0 >> 2) + c];
            wr[r] = wg[(size_t)(k0 + T) * (NE / 4) + c];
        }
    };
    auto write_step = [&]() {
#pragma unroll
        for (int r = 0; r < 4; ++r) {
            int idx = tid + 256 * r;
            int T = idx >> 4, c = idx & 15;
            *reinterpret_cast<float4*>(&xs[T * XS_STRIDE + c * 4]) = xr[r];
            *reinterpret_cast<float4*>(&ws[T * NE + c * 4])        = wr[r];
        }
    };
    auto fold = [&]() {
#pragma unroll
        for (int i = 0; i < 4; ++i)
#pragma unroll
            for (int j = 0; j < 4; ++j) { tot[i][j] += acc[i][j]; acc[i][j] = 0.0f; }
    };

    load_step(0);
    for (int s = 0; s < DIM / BK; ++s) {
        __syncthreads();
        write_step();
        __syncthreads();
        if (s + 1 < DIM / BK) load_step((s + 1) * BK);
#pragma unroll
        for (int kq = 0; kq < 16; ++kq) {
            float xf[4][4], wf[4][4];
#pragma unroll
            for (int i = 0; i < 4; ++i)
                *reinterpret_cast<float4*>(xf[i]) =
                    *reinterpret_cast<const float4*>(&xs[(t0 + i) * XS_STRIDE + kq * 4]);
#pragma unroll
            for (int kk = 0; kk < 4; ++kk)
                *reinterpret_cast<float4*>(wf[kk]) =
                    *reinterpret_cast<const float4*>(&ws[(kq * 4 + kk) * NE + e0]);
#pragma unroll
            for (int kk = 0; kk < 4; ++kk)
#pragma unroll
                for (int i = 0; i < 4; ++i)
#pragma unroll
                    for (int j = 0; j < 4; ++j)
                        acc[i][j] = fmaf(xf[i][kk], wf[kk][j], acc[i][j]);
            if (kq == 7 && s == 59) fold();
        }
        if ((s % 5) == 4 && s <= 54) fold();
    }
    fold();

    __syncthreads();
#pragma unroll
    for (int i = 0; i < 4; ++i)
        *reinterpret_cast<float4*>(&xs[(t0 + i) * XS_STRIDE + e0]) =
            *reinterpret_cast<float4*>(tot[i]);
    __syncthreads();

    const int lane = tid & 63;
    const int wid  = tid >> 6;
    float* outI = out;
    float* outG = out + (size_t)N_TOKENS * TOPK;

    for (int tt = 0; tt < 16; ++tt) {
        const int t = wid * 16 + tt;
        float v = xs[t * XS_STRIDE + lane];
        float m = v;
#pragma unroll
        for (int off = 32; off; off >>= 1) m = fmaxf(m, __shfl_xor(m, off));
        float e = expf(v - m);
        float ssum = e;
#pragma unroll
        for (int off = 32; off; off >>= 1) ssum += __shfl_xor(ssum, off);
        float g = e / ssum;

        float curv = v;
        const int idx = lane;
        float myi = 0.0f, myg = 0.0f;
#pragma unroll
        for (int r = 0; r < TOPK; ++r) {
            float bv = curv;
            int   bi = idx;
#pragma unroll
            for (int off = 32; off; off >>= 1) {
                float ov = __shfl_xor(bv, off);
                int   oi = __shfl_xor(bi, off);
                if (ov > bv || (ov == bv && oi < bi)) { bv = ov; bi = oi; }
            }
            float wgv = __shfl(g, bi);
            if (lane == r) { myi = (float)bi; myg = wgv; }
            if (idx == bi) curv = -INFINITY;
        }
        const int gt = bt0 + t;
        if (lane < TOPK) {
            outI[(size_t)gt * TOPK + lane] = myi;
            outG[(size_t)gt * TOPK + lane] = myg;
        }
    }
}

extern "C" void kernel_launch(void* const* d_in, const int* in_sizes, int n_in,
                              void* d_out, int out_size, void* d_ws, size_t ws_size,
                              hipStream_t stream) {
    const float* x = (const float*)d_in[0];
    const float* w = (const float*)d_in[1];
    float* out = (float*)d_out;
    const size_t needed = (size_t)NCHUNK * N_TOKENS * NE * sizeof(float);  // 54.5 MB
    if (ws_size >= needed) {
        float* part = (float*)d_ws;
        gate_pass1<<<dim3(NT1, NCHUNK), dim3(256), 0, stream>>>(x, w, part);
        gate_pass2<<<dim3(N_TOKENS / 8), dim3(256), 0, stream>>>(part, out);
    } else {
        topk_gating_blas<<<dim3(N_TOKENS / TM), dim3(256), 0, stream>>>(x, w, out);
    }
}

// Round 11
// 164.369 us; speedup vs baseline: 2.1088x; 1.1775x over previous
//
#include <hip/hip_runtime.h>
#include <hip/hip_bf16.h>
#include <math.h>

#define N_TOKENS 16384
#define DIM      4096
#define NE       64
#define TOPK     8
#define NCHUNK   13     // OpenBLAS Kc blocks: [320 x 11, 288, 288]
#define TM1      256    // pass1 tokens per block
#define BK1      16     // pass1 K-step (320=20*16, 288=18*16)
#define NT1      (N_TOKENS / TM1)   // 64 token tiles

// HBM -> LDS direct (no VGPR round-trip). LDS dest must be wave-uniform.
__device__ __forceinline__ void gld16(const float* g, float* l) {
    __builtin_amdgcn_global_load_lds(
        (const __attribute__((address_space(1))) void*)g,
        (__attribute__((address_space(3))) void*)l, 16, 0, 0);
}

// ---------------- Pass 1: one OpenBLAS K-chunk per block.y ----------------
// part[b][token][expert]. Micro-tile 8 tok x 8 exp (1.0 B/FMA LDS traffic).
// BK=16 keeps LDS at 40KB -> 4 blocks/CU (round 10's 80KB gave 1 block/CU,
// 10% occupancy, 30% VALUBusy). global_load_lds staging (no spills, r10).
// x rows are 64B; XOR-swizzle c4^=(row&3) via pre-swizzled GLOBAL source
// (LDS linear, rule #21); read un-swizzles with kq^(tg&3) -> 2-way (free).
__global__ __launch_bounds__(256) void gate_pass1(
    const float* __restrict__ x, const float* __restrict__ w, float* __restrict__ part)
{
    __shared__ float xs[2][TM1 * BK1];  // 2 x 16 KB
    __shared__ float ws[2][BK1 * NE];   // 2 x  4 KB

    const int tid  = threadIdx.x;
    const int lane = tid & 63;
    const int wid  = tid >> 6;
    const int eg   = tid & 7;        // expert group (8 experts)
    const int tg   = tid >> 3;       // token base 0..31
    const int e0   = eg * 8;
    const int g0   = blockIdx.x * TM1;
    const int b    = blockIdx.y;
    const int kstart = (b < 12) ? 320 * b : 3808;
    const int nsteps = (b < 11) ? 20 : 18;

    float acc[8][8];
#pragma unroll
    for (int i = 0; i < 8; ++i)
#pragma unroll
        for (int j = 0; j < 8; ++j) acc[i][j] = 0.0f;

    // Per-lane staging geometry (constant):
    const int xrow = lane >> 2;                 // row within a 16-row call
    const int c4s  = (lane & 3) ^ (xrow & 3);   // pre-swizzled float4 col of x
    const int wrow = lane >> 4;                 // row within a 4-row w call
    const int wc4  = lane & 15;

    auto stage = [&](int buf, int k0) {
        // x: 256 rows x 16 floats; wave wid covers rows wid*64..+63 (4 calls)
#pragma unroll
        for (int q = 0; q < 4; ++q) {
            const int rowbase = wid * 64 + q * 16;
            const float* src = x + (size_t)(g0 + rowbase + xrow) * DIM + k0 + c4s * 4;
            gld16(src, &xs[buf][rowbase * BK1]);        // wave-uniform dest
        }
        // w: 16 rows x 64 floats; wave wid covers rows wid*4..+3 (1 call)
        {
            const float* src = w + (size_t)(k0 + wid * 4 + wrow) * NE + wc4 * 4;
            gld16(src, &ws[buf][wid * 4 * NE]);         // wave-uniform dest
        }
    };

    stage(0, kstart);
    int cur = 0;
    const int tg3 = tg & 3;
    for (int s = 0; s < nsteps; ++s) {
        __syncthreads();   // drains vmcnt: buf[cur] ready; prev compute done
        if (s + 1 < nsteps) stage(cur ^ 1, kstart + BK1 * (s + 1));

#pragma unroll
        for (int kq = 0; kq < 4; ++kq) {
            float wf[4][8];   // 4 k-values x 8 experts
#pragma unroll
            for (int kk = 0; kk < 4; ++kk) {
                *reinterpret_cast<float4*>(&wf[kk][0]) =
                    *reinterpret_cast<const float4*>(&ws[cur][(kq * 4 + kk) * NE + e0]);
                *reinterpret_cast<float4*>(&wf[kk][4]) =
                    *reinterpret_cast<const float4*>(&ws[cur][(kq * 4 + kk) * NE + e0 + 4]);
            }
            const int kqs = (kq ^ tg3) * 4;   // un-swizzle on read
            // Per (token i, expert j): kk 0..3, kq 0..3, steps ascend
            // -> strictly ascending k within the chunk (exact BLAS chain).
#pragma unroll
            for (int i = 0; i < 8; ++i) {
                float xv[4];
                *reinterpret_cast<float4*>(xv) =
                    *reinterpret_cast<const float4*>(&xs[cur][(tg + 32 * i) * BK1 + kqs]);
#pragma unroll
                for (int kk = 0; kk < 4; ++kk)
#pragma unroll
                    for (int j = 0; j < 8; ++j)
                        acc[i][j] = fmaf(xv[kk], wf[kk][j], acc[i][j]);
            }
        }
        cur ^= 1;
    }

    float* pt = part + ((size_t)b * N_TOKENS + g0) * NE;
#pragma unroll
    for (int i = 0; i < 8; ++i) {
        *reinterpret_cast<float4*>(&pt[(tg + 32 * i) * NE + e0]) =
            *reinterpret_cast<float4*>(&acc[i][0]);
        *reinterpret_cast<float4*>(&pt[(tg + 32 * i) * NE + e0 + 4]) =
            *reinterpret_cast<float4*>(&acc[i][4]);
    }
}

// ------- Pass 2: fold 13 partials ascending (exact ref tree) + epilogue -------
// 2048 blocks x 4 waves; each wave = 2 tokens, lane = expert.
__global__ __launch_bounds__(256) void gate_pass2(
    const float* __restrict__ part, float* __restrict__ out)
{
    const int tid  = threadIdx.x;
    const int lane = tid & 63;
    const int wid  = tid >> 6;
    float* outI = out;
    float* outG = out + (size_t)N_TOKENS * TOPK;

#pragma unroll
    for (int tt = 0; tt < 2; ++tt) {
        const int g = blockIdx.x * 8 + wid * 2 + tt;

        // left-fold ascending b: ((B0+B1)+...)+B12  (0+B0 == B0 bit-exactly)
        float v = 0.0f;
#pragma unroll
        for (int bb = 0; bb < NCHUNK; ++bb)
            v += part[((size_t)bb * N_TOKENS + g) * NE + lane];

        float m = v;
#pragma unroll
        for (int off = 32; off; off >>= 1) m = fmaxf(m, __shfl_xor(m, off));
        float e = expf(v - m);
        float ssum = e;
#pragma unroll
        for (int off = 32; off; off >>= 1) ssum += __shfl_xor(ssum, off);
        float gte = e / ssum;

        // top-8 on logits (monotone == gate rank), ties -> lower index
        float curv = v;
        const int idx = lane;
        float myi = 0.0f, myg = 0.0f;
#pragma unroll
        for (int r = 0; r < TOPK; ++r) {
            float bv = curv;
            int   bi = idx;
#pragma unroll
            for (int off = 32; off; off >>= 1) {
                float ov = __shfl_xor(bv, off);
                int   oi = __shfl_xor(bi, off);
                if (ov > bv || (ov == bv && oi < bi)) { bv = ov; bi = oi; }
            }
            float wgv = __shfl(gte, bi);
            if (lane == r) { myi = (float)bi; myg = wgv; }
            if (idx == bi) curv = -INFINITY;
        }
        if (lane < TOPK) {
            outI[(size_t)g * TOPK + lane] = myi;
            outG[(size_t)g * TOPK + lane] = myg;
        }
    }
}

// ---------------- Fallback: verified single-pass round-5 kernel ----------------
#define TM 64
#define BK 64
#define XS_STRIDE 68
__global__ __launch_bounds__(256) void topk_gating_blas(
    const float* __restrict__ x, const float* __restrict__ w, float* __restrict__ out)
{
    __shared__ float xs[TM * XS_STRIDE];
    __shared__ float ws[BK * NE];

    const int tid = threadIdx.x;
    const int eg  = tid & 15;
    const int tg  = tid >> 4;
    const int e0  = eg * 4;
    const int t0  = tg * 4;
    const int bt0 = blockIdx.x * TM;

    float acc[4][4], tot[4][4];
#pragma unroll
    for (int i = 0; i < 4; ++i)
#pragma unroll
        for (int j = 0; j < 4; ++j) { acc[i][j] = 0.0f; tot[i][j] = 0.0f; }

    const float4* xg = reinterpret_cast<const float4*>(x);
    const float4* wg = reinterpret_cast<const float4*>(w);
    float4 xr[4], wr[4];

    auto load_step = [&](int k0) {
#pragma unroll
        for (int r = 0; r < 4; ++r) {
            int idx = tid + 256 * r;
            int T = idx >> 4, c = idx & 15;
            xr[r] = xg[(size_t)(bt0 + T) * (DIM / 4) + (k0 >> 2) + c];
            wr[r] = wg[(size_t)(k0 + T) * (NE / 4) + c];
        }
    };
    auto write_step = [&]() {
#pragma unroll
        for (int r = 0; r < 4; ++r) {
            int idx = tid + 256 * r;
            int T = idx >> 4, c = idx & 15;
            *reinterpret_cast<float4*>(&xs[T * XS_STRIDE + c * 4]) = xr[r];
            *reinterpret_cast<float4*>(&ws[T * NE + c * 4])        = wr[r];
        }
    };
    auto fold = [&]() {
#pragma unroll
        for (int i = 0; i < 4; ++i)
#pragma unroll
            for (int j = 0; j < 4; ++j) { tot[i][j] += acc[i][j]; acc[i][j] = 0.0f; }
    };

    load_step(0);
    for (int s = 0; s < DIM / BK; ++s) {
        __syncthreads();
        write_step();
        __syncthreads();
        if (s + 1 < DIM / BK) load_step((s + 1) * BK);
#pragma unroll
        for (int kq = 0; kq < 16; ++kq) {
            float xf[4][4], wf[4][4];
#pragma unroll
            for (int i = 0; i < 4; ++i)
                *reinterpret_cast<float4*>(xf[i]) =
                    *reinterpret_cast<const float4*>(&xs[(t0 + i) * XS_STRIDE + kq * 4]);
#pragma unroll
            for (int kk = 0; kk < 4; ++kk)
                *reinterpret_cast<float4*>(wf[kk]) =
                    *reinterpret_cast<const float4*>(&ws[(kq * 4 + kk) * NE + e0]);
#pragma unroll
            for (int kk = 0; kk < 4; ++kk)
#pragma unroll
                for (int i = 0; i < 4; ++i)
#pragma unroll
                    for (int j = 0; j < 4; ++j)
                        acc[i][j] = fmaf(xf[i][kk], wf[kk][j], acc[i][j]);
            if (kq == 7 && s == 59) fold();
        }
        if ((s % 5) == 4 && s <= 54) fold();
    }
    fold();

    __syncthreads();
#pragma unroll
    for (int i = 0; i < 4; ++i)
        *reinterpret_cast<float4*>(&xs[(t0 + i) * XS_STRIDE + e0]) =
            *reinterpret_cast<float4*>(tot[i]);
    __syncthreads();

    const int lane = tid & 63;
    const int wid  = tid >> 6;
    float* outI = out;
    float* outG = out + (size_t)N_TOKENS * TOPK;

    for (int tt = 0; tt < 16; ++tt) {
        const int t = wid * 16 + tt;
        float v = xs[t * XS_STRIDE + lane];
        float m = v;
#pragma unroll
        for (int off = 32; off; off >>= 1) m = fmaxf(m, __shfl_xor(m, off));
        float e = expf(v - m);
        float ssum = e;
#pragma unroll
        for (int off = 32; off; off >>= 1) ssum += __shfl_xor(ssum, off);
        float g = e / ssum;

        float curv = v;
        const int idx = lane;
        float myi = 0.0f, myg = 0.0f;
#pragma unroll
        for (int r = 0; r < TOPK; ++r) {
            float bv = curv;
            int   bi = idx;
#pragma unroll
            for (int off = 32; off; off >>= 1) {
                float ov = __shfl_xor(bv, off);
                int   oi = __shfl_xor(bi, off);
                if (ov > bv || (ov == bv && oi < bi)) { bv = ov; bi = oi; }
            }
            float wgv = __shfl(g, bi);
            if (lane == r) { myi = (float)bi; myg = wgv; }
            if (idx == bi) curv = -INFINITY;
        }
        const int gt = bt0 + t;
        if (lane < TOPK) {
            outI[(size_t)gt * TOPK + lane] = myi;
            outG[(size_t)gt * TOPK + lane] = myg;
        }
    }
}

extern "C" void kernel_launch(void* const* d_in, const int* in_sizes, int n_in,
                              void* d_out, int out_size, void* d_ws, size_t ws_size,
                              hipStream_t stream) {
    const float* x = (const float*)d_in[0];
    const float* w = (const float*)d_in[1];
    float* out = (float*)d_out;
    const size_t needed = (size_t)NCHUNK * N_TOKENS * NE * sizeof(float);  // 54.5 MB
    if (ws_size >= needed) {
        float* part = (float*)d_ws;
        gate_pass1<<<dim3(NT1, NCHUNK), dim3(256), 0, stream>>>(x, w, part);
        gate_pass2<<<dim3(N_TOKENS / 8), dim3(256), 0, stream>>>(part, out);
    } else {
        topk_gating_blas<<<dim3(N_TOKENS / TM), dim3(256), 0, stream>>>(x, w, out);
    }
}